// Round 1
// baseline (873.380 us; speedup 1.0000x reference)
//
#include <hip/hip_runtime.h>
#include <hip/hip_bf16.h>

#define DIM 1024
#define BB  32
#define SS  2048

typedef __attribute__((ext_vector_type(8))) short bf16x8;
typedef __attribute__((ext_vector_type(4))) float f32x4;
typedef unsigned short ushort_t;

__device__ __forceinline__ ushort_t f2bf(float f) {
    unsigned int u = __builtin_bit_cast(unsigned int, f);
    u += 0x7FFFu + ((u >> 16) & 1u);   // round-to-nearest-even
    return (ushort_t)(u >> 16);
}

// ---------------------------------------------------------------- K0: W2 -> bf16
__global__ void k_w2convert(const float* __restrict__ w2, ushort_t* __restrict__ w2bf) {
    int i = (blockIdx.x * 256 + threadIdx.x) * 8;   // 512 blocks * 256 thr * 8 = 1M
    const float4* p = (const float4*)(w2 + i);
    float4 a = p[0], b = p[1];
    unsigned int r0 = (unsigned)f2bf(a.x) | ((unsigned)f2bf(a.y) << 16);
    unsigned int r1 = (unsigned)f2bf(a.z) | ((unsigned)f2bf(a.w) << 16);
    unsigned int r2 = (unsigned)f2bf(b.x) | ((unsigned)f2bf(b.y) << 16);
    unsigned int r3 = (unsigned)f2bf(b.z) | ((unsigned)f2bf(b.w) << 16);
    uint4 o = make_uint4(r0, r1, r2, r3);
    *(uint4*)(w2bf + i) = o;
}

// ---------------------------------------------------------------- K1: qb = query@W1^T + W1_b + W2_b ; zero context
__global__ void k_qb(const float* __restrict__ query, const float* __restrict__ w1w,
                     const float* __restrict__ w1b, const float* __restrict__ w2b,
                     float* __restrict__ qb, float* __restrict__ context) {
    int bid = blockIdx.x;            // 128 = 32 b * 4 echunks
    int tid = threadIdx.x;           // 256
    context[bid * 256 + tid] = 0.0f; // zero all 32768 context floats
    int b = bid >> 2;
    int e = (bid & 3) * 256 + tid;
    __shared__ float qs[DIM];
    for (int i = tid; i < DIM; i += 256) qs[i] = query[b * DIM + i];
    __syncthreads();
    const float4* wp = (const float4*)(w1w + (size_t)e * DIM);
    const float4* qp = (const float4*)qs;
    float s = 0.0f;
#pragma unroll 4
    for (int d = 0; d < DIM / 4; ++d) {
        float4 w = wp[d], q = qp[d];
        s = fmaf(w.x, q.x, s); s = fmaf(w.y, q.y, s);
        s = fmaf(w.z, q.z, s); s = fmaf(w.w, q.w, s);
    }
    qb[b * DIM + e] = s + w1b[e] + w2b[e];
}

// ---------------------------------------------------------------- K2: fused score = V . tanh(key@W2^T + qb)
// grid 1024 (64 rows each), block 512 (8 waves). Wave w owns N-cols [w*128, w*128+128).
__global__ __launch_bounds__(512, 2)
void k_score(const float* __restrict__ key, const ushort_t* __restrict__ w2bf,
             const float* __restrict__ qb, const float* __restrict__ vw,
             const float* __restrict__ vb, float* __restrict__ score) {
    __shared__ uint4 smemv[4096];      // 64 KiB: one K-half of the A tile (64 x 512 bf16, swizzled)
    char* smem = (char*)smemv;
    const int tid  = threadIdx.x;
    const int lane = tid & 63;
    const int w    = tid >> 6;
    const int l15  = lane & 15;
    const int l4   = lane >> 4;
    const int rb   = blockIdx.x * 64;  // global row base (b,s flattened)
    const int b    = rb >> 11;         // / 2048

    // per-wave column params (col = w*128 + sub*16 + l15)
    float qsub[8], vsub[8];
#pragma unroll
    for (int s = 0; s < 8; ++s) {
        int c = w * 128 + s * 16 + l15;
        qsub[s] = qb[b * DIM + c];
        vsub[s] = vw[c];
    }

    f32x4 acc[4][8];
#pragma unroll
    for (int mi = 0; mi < 4; ++mi)
#pragma unroll
        for (int s = 0; s < 8; ++s) acc[mi][s] = (f32x4){0.f, 0.f, 0.f, 0.f};

    for (int h = 0; h < 2; ++h) {       // two K-halves of 512
        __syncthreads();
        // ---- stage A half: 64 rows x 512 k, fp32 -> bf16, swizzled LDS
#pragma unroll
        for (int u = 0; u < 8; ++u) {
            int flat8 = u * 512 + tid;        // 4096 units of 8 floats
            int r  = flat8 >> 6;              // row 0..63
            int kc = flat8 & 63;              // 8-float chunk in row
            const float4* gp = (const float4*)(key + (size_t)(rb + r) * DIM + h * 512 + kc * 8);
            float4 a0 = gp[0], a1 = gp[1];
            unsigned int p0 = (unsigned)f2bf(a0.x) | ((unsigned)f2bf(a0.y) << 16);
            unsigned int p1 = (unsigned)f2bf(a0.z) | ((unsigned)f2bf(a0.w) << 16);
            unsigned int p2 = (unsigned)f2bf(a1.x) | ((unsigned)f2bf(a1.y) << 16);
            unsigned int p3 = (unsigned)f2bf(a1.z) | ((unsigned)f2bf(a1.w) << 16);
            int off = (r * 1024 + kc * 16) ^ ((r & 7) << 4);
            *(uint4*)(smem + off) = make_uint4(p0, p1, p2, p3);
        }
        __syncthreads();
        // ---- K loop over this half: 16 steps of BK=32
        for (int kk = 0; kk < 16; ++kk) {
            bf16x8 af[4];
#pragma unroll
            for (int mi = 0; mi < 4; ++mi) {
                int row = mi * 16 + l15;
                int off = (row * 1024 + kk * 64 + l4 * 16) ^ ((row & 7) << 4);
                af[mi] = *(const bf16x8*)(smem + off);
            }
            int kbase = h * 512 + kk * 32 + l4 * 8;
#pragma unroll
            for (int s = 0; s < 8; ++s) {
                int ncol = w * 128 + s * 16 + l15;
                bf16x8 bf = *(const bf16x8*)(w2bf + ncol * DIM + kbase);
#pragma unroll
                for (int mi = 0; mi < 4; ++mi)
                    acc[mi][s] = __builtin_amdgcn_mfma_f32_16x16x32_bf16(af[mi], bf, acc[mi][s], 0, 0, 0);
            }
        }
    }

    // ---- epilogue: score_partial[row] = sum_cols V[c] * tanh(acc + qb[c])
    float psum[4][4];
#pragma unroll
    for (int mi = 0; mi < 4; ++mi)
#pragma unroll
        for (int r = 0; r < 4; ++r) psum[mi][r] = 0.f;
#pragma unroll
    for (int mi = 0; mi < 4; ++mi)
#pragma unroll
        for (int s = 0; s < 8; ++s) {
            float q = qsub[s], v = vsub[s];
#pragma unroll
            for (int r = 0; r < 4; ++r) {
                float x = acc[mi][s][r] + q;
                psum[mi][r] = fmaf(v, tanhf(x), psum[mi][r]);
            }
        }
    // reduce across the 16 cols (lanes sharing l4)
#pragma unroll
    for (int mi = 0; mi < 4; ++mi)
#pragma unroll
        for (int r = 0; r < 4; ++r) {
            float t = psum[mi][r];
            t += __shfl_xor(t, 1); t += __shfl_xor(t, 2);
            t += __shfl_xor(t, 4); t += __shfl_xor(t, 8);
            psum[mi][r] = t;
        }
    __syncthreads();                    // done reading A tile; reuse LDS
    float* part = (float*)smemv;        // [8 waves][64 rows]
    if (l15 == 0) {
#pragma unroll
        for (int mi = 0; mi < 4; ++mi)
#pragma unroll
            for (int r = 0; r < 4; ++r) {
                int row = mi * 16 + l4 * 4 + r;
                part[w * 64 + row] = psum[mi][r];
            }
    }
    __syncthreads();
    if (tid < 64) {
        float s = 0.f;
#pragma unroll
        for (int ww = 0; ww < 8; ++ww) s += part[ww * 64 + tid];
        score[rb + tid] = s + vb[0];
    }
}

// ---------------------------------------------------------------- K3: softmax over S per b
__global__ void k_softmax(const float* __restrict__ score, float* __restrict__ attn) {
    int b = blockIdx.x, tid = threadIdx.x;   // 32 blocks, 256 threads, 8 vals/thread
    float v[8];
    float m = -1e30f;
#pragma unroll
    for (int i = 0; i < 8; ++i) {
        v[i] = score[b * SS + i * 256 + tid];
        m = fmaxf(m, v[i]);
    }
#pragma unroll
    for (int mask = 1; mask < 64; mask <<= 1) m = fmaxf(m, __shfl_xor(m, mask));
    __shared__ float redm[4], reds[4];
    if ((tid & 63) == 0) redm[tid >> 6] = m;
    __syncthreads();
    m = fmaxf(fmaxf(redm[0], redm[1]), fmaxf(redm[2], redm[3]));
    float e[8], sum = 0.f;
#pragma unroll
    for (int i = 0; i < 8; ++i) { e[i] = expf(v[i] - m); sum += e[i]; }
#pragma unroll
    for (int mask = 1; mask < 64; mask <<= 1) sum += __shfl_xor(sum, mask);
    if ((tid & 63) == 0) reds[tid >> 6] = sum;
    __syncthreads();
    sum = reds[0] + reds[1] + reds[2] + reds[3];
    float inv = 1.0f / sum;
#pragma unroll
    for (int i = 0; i < 8; ++i) attn[b * SS + i * 256 + tid] = e[i] * inv;
}

// ---------------------------------------------------------------- K4: context = attn @ value
__global__ void k_context(const float* __restrict__ attn, const float* __restrict__ value,
                          float* __restrict__ context) {
    int bid = blockIdx.x;        // 1024 = 32 b * 32 schunks
    int b = bid >> 5, sc = bid & 31;
    int tid = threadIdx.x;       // 256 threads -> 1024 d-cols via float4
    int s0 = sc * 64;
    const float4* vp = (const float4*)value + ((size_t)b * SS + s0) * 256 + tid;
    const float* ap = attn + b * SS + s0;
    float4 acc = make_float4(0.f, 0.f, 0.f, 0.f);
#pragma unroll 4
    for (int s = 0; s < 64; ++s) {
        float a = ap[s];
        float4 v = vp[(size_t)s * 256];
        acc.x = fmaf(a, v.x, acc.x);
        acc.y = fmaf(a, v.y, acc.y);
        acc.z = fmaf(a, v.z, acc.z);
        acc.w = fmaf(a, v.w, acc.w);
    }
    float* cp = context + b * DIM + tid * 4;
    atomicAdd(cp + 0, acc.x);
    atomicAdd(cp + 1, acc.y);
    atomicAdd(cp + 2, acc.z);
    atomicAdd(cp + 3, acc.w);
}

// ----------------------------------------------------------------
extern "C" void kernel_launch(void* const* d_in, const int* in_sizes, int n_in,
                              void* d_out, int out_size, void* d_ws, size_t ws_size,
                              hipStream_t stream) {
    const float* query = (const float*)d_in[0];
    const float* key   = (const float*)d_in[1];
    const float* value = (const float*)d_in[2];
    const float* w1w   = (const float*)d_in[3];
    const float* w1b   = (const float*)d_in[4];
    const float* w2w   = (const float*)d_in[5];
    const float* w2b   = (const float*)d_in[6];
    const float* vw    = (const float*)d_in[7];
    const float* vb    = (const float*)d_in[8];

    float* out     = (float*)d_out;
    float* context = out;                 // [32,1024]
    float* attn    = out + BB * DIM;      // [32,2048]

    char* ws = (char*)d_ws;
    ushort_t* w2bf = (ushort_t*)ws;                                   // 2 MiB
    float* qb      = (float*)(ws + (2u << 20));                       // 128 KiB
    float* score   = (float*)(ws + (2u << 20) + (128u << 10));        // 256 KiB

    k_w2convert<<<512, 256, 0, stream>>>(w2w, w2bf);
    k_qb<<<128, 256, 0, stream>>>(query, w1w, w1b, w2b, qb, context);
    k_score<<<1024, 512, 0, stream>>>(key, w2bf, qb, vw, vb, score);
    k_softmax<<<BB, 256, 0, stream>>>(score, attn);
    k_context<<<1024, 256, 0, stream>>>(attn, value, context);
}

// Round 2
// 721.007 us; speedup vs baseline: 1.2113x; 1.2113x over previous
//
#include <hip/hip_runtime.h>
#include <hip/hip_bf16.h>

#define DIM 1024
#define BB  32
#define SS  2048

typedef __attribute__((ext_vector_type(8))) short bf16x8;
typedef __attribute__((ext_vector_type(4))) float f32x4;
typedef unsigned short ushort_t;

__device__ __forceinline__ ushort_t f2bf(float f) {
    unsigned int u = __builtin_bit_cast(unsigned int, f);
    u += 0x7FFFu + ((u >> 16) & 1u);   // round-to-nearest-even
    return (ushort_t)(u >> 16);
}

__device__ __forceinline__ float fast_tanh(float x) {
    float z = __expf(2.0f * x);                       // v_exp path
    return 1.0f - 2.0f * __builtin_amdgcn_rcpf(z + 1.0f);
}

// ---------------------------------------------------------------- K0: W2 -> bf16 fragment-ordered
// frag[chunk][lane][8], chunk = ((w*8+s)*2+h)*16+kk ; element (col,k) =
// (w*128+s*16+(lane&15), h*512+kk*32+(lane>>4)*8 + j) — matches k_score's MFMA B fragment.
__global__ void k_w2frag(const float* __restrict__ w2, ushort_t* __restrict__ frag) {
    int t = blockIdx.x * 256 + threadIdx.x;   // 512 blocks -> 131072 = 2048 chunks * 64 lanes
    int lane  = t & 63;
    int chunk = t >> 6;
    int kk = chunk & 15;
    int h  = (chunk >> 4) & 1;
    int s  = (chunk >> 5) & 7;
    int w  = (chunk >> 8) & 7;
    int col = w * 128 + s * 16 + (lane & 15);
    int k   = h * 512 + kk * 32 + (lane >> 4) * 8;
    const float4* p = (const float4*)(w2 + (size_t)col * DIM + k);
    float4 a = p[0], b = p[1];
    unsigned int r0 = (unsigned)f2bf(a.x) | ((unsigned)f2bf(a.y) << 16);
    unsigned int r1 = (unsigned)f2bf(a.z) | ((unsigned)f2bf(a.w) << 16);
    unsigned int r2 = (unsigned)f2bf(b.x) | ((unsigned)f2bf(b.y) << 16);
    unsigned int r3 = (unsigned)f2bf(b.z) | ((unsigned)f2bf(b.w) << 16);
    *(uint4*)(frag + (size_t)chunk * 512 + lane * 8) = make_uint4(r0, r1, r2, r3);
}

// ---------------------------------------------------------------- K1: qb = query@W1^T + W1_b + W2_b
// 256 blocks = 32 b * 8 echunks; wave-per-row coalesced loads + shuffle reduce.
__global__ void k_qb(const float* __restrict__ query, const float* __restrict__ w1w,
                     const float* __restrict__ w1b, const float* __restrict__ w2b,
                     float* __restrict__ qb) {
    int bid = blockIdx.x;
    int b = bid >> 3, ec = bid & 7;
    int tid = threadIdx.x, lane = tid & 63, w = tid >> 6;
    __shared__ float qs[DIM];
    ((float4*)qs)[tid] = ((const float4*)(query + (size_t)b * DIM))[tid];
    __syncthreads();
    for (int i = 0; i < 32; ++i) {
        int e = ec * 128 + w * 32 + i;
        const float4* wp = (const float4*)(w1w + (size_t)e * DIM);
        float s = 0.0f;
#pragma unroll
        for (int c = 0; c < 4; ++c) {
            float4 wv = wp[c * 64 + lane];
            float4 qv = ((const float4*)qs)[c * 64 + lane];
            s = fmaf(wv.x, qv.x, s); s = fmaf(wv.y, qv.y, s);
            s = fmaf(wv.z, qv.z, s); s = fmaf(wv.w, qv.w, s);
        }
#pragma unroll
        for (int mask = 1; mask < 64; mask <<= 1) s += __shfl_xor(s, mask);
        if (lane == 0) qb[b * DIM + e] = s + w1b[e] + w2b[e];
    }
}

// ---------------------------------------------------------------- K2: fused score = V . tanh(key@W2^T + qb)
// grid 1024 (64 rows each), block 512 (8 waves). Wave w owns N-cols [w*128, w*128+128).
__global__ __launch_bounds__(512, 2)
void k_score(const float* __restrict__ key, const ushort_t* __restrict__ w2frag,
             const float* __restrict__ qb, const float* __restrict__ vw,
             const float* __restrict__ vb, float* __restrict__ score) {
    __shared__ uint4 smemv[4096];      // 64 KiB: one K-half of the A tile (64 x 512 bf16, swizzled)
    char* smem = (char*)smemv;
    const int tid  = threadIdx.x;
    const int lane = tid & 63;
    const int w    = tid >> 6;
    const int l15  = lane & 15;
    const int l4   = lane >> 4;
    const int rb   = blockIdx.x * 64;  // global row base (b,s flattened)
    const int b    = rb >> 11;         // / 2048

    float qsub[8], vsub[8];
#pragma unroll
    for (int s = 0; s < 8; ++s) {
        int c = w * 128 + s * 16 + l15;
        qsub[s] = qb[b * DIM + c];
        vsub[s] = vw[c];
    }

    f32x4 acc[4][8];
#pragma unroll
    for (int mi = 0; mi < 4; ++mi)
#pragma unroll
        for (int s = 0; s < 8; ++s) acc[mi][s] = (f32x4){0.f, 0.f, 0.f, 0.f};

    for (int h = 0; h < 2; ++h) {       // two K-halves of 512
        __syncthreads();
        // ---- stage A half: 64 rows x 512 k, fp32 -> bf16, swizzled LDS
#pragma unroll
        for (int u = 0; u < 8; ++u) {
            int flat8 = u * 512 + tid;        // 4096 units of 8 floats
            int r  = flat8 >> 6;              // row 0..63
            int kc = flat8 & 63;              // 8-float chunk in row
            const float4* gp = (const float4*)(key + (size_t)(rb + r) * DIM + h * 512 + kc * 8);
            float4 a0 = gp[0], a1 = gp[1];
            unsigned int p0 = (unsigned)f2bf(a0.x) | ((unsigned)f2bf(a0.y) << 16);
            unsigned int p1 = (unsigned)f2bf(a0.z) | ((unsigned)f2bf(a0.w) << 16);
            unsigned int p2 = (unsigned)f2bf(a1.x) | ((unsigned)f2bf(a1.y) << 16);
            unsigned int p3 = (unsigned)f2bf(a1.z) | ((unsigned)f2bf(a1.w) << 16);
            int off = (r * 1024 + kc * 16) ^ ((r & 7) << 4);
            *(uint4*)(smem + off) = make_uint4(p0, p1, p2, p3);
        }
        __syncthreads();
        // ---- K loop over this half: 16 steps of BK=32
        for (int kk = 0; kk < 16; ++kk) {
            bf16x8 af[4];
#pragma unroll
            for (int mi = 0; mi < 4; ++mi) {
                int row = mi * 16 + l15;
                int off = (row * 1024 + kk * 64 + l4 * 16) ^ ((row & 7) << 4);
                af[mi] = *(const bf16x8*)(smem + off);
            }
#pragma unroll
            for (int s = 0; s < 8; ++s) {
                // coalesced fragment load: 64 lanes * 16B contiguous
                int chunk = ((w * 8 + s) * 2 + h) * 16 + kk;
                bf16x8 bfv = *(const bf16x8*)(w2frag + (size_t)chunk * 512 + lane * 8);
#pragma unroll
                for (int mi = 0; mi < 4; ++mi)
                    acc[mi][s] = __builtin_amdgcn_mfma_f32_16x16x32_bf16(af[mi], bfv, acc[mi][s], 0, 0, 0);
            }
        }
    }

    // ---- epilogue: score_partial[row] = sum_cols V[c] * tanh(acc + qb[c])
    float psum[4][4];
#pragma unroll
    for (int mi = 0; mi < 4; ++mi)
#pragma unroll
        for (int r = 0; r < 4; ++r) psum[mi][r] = 0.f;
#pragma unroll
    for (int mi = 0; mi < 4; ++mi)
#pragma unroll
        for (int s = 0; s < 8; ++s) {
            float q = qsub[s], v = vsub[s];
#pragma unroll
            for (int r = 0; r < 4; ++r) {
                float x = acc[mi][s][r] + q;
                psum[mi][r] = fmaf(v, fast_tanh(x), psum[mi][r]);
            }
        }
#pragma unroll
    for (int mi = 0; mi < 4; ++mi)
#pragma unroll
        for (int r = 0; r < 4; ++r) {
            float t = psum[mi][r];
            t += __shfl_xor(t, 1); t += __shfl_xor(t, 2);
            t += __shfl_xor(t, 4); t += __shfl_xor(t, 8);
            psum[mi][r] = t;
        }
    __syncthreads();                    // done reading A tile; reuse LDS
    float* part = (float*)smemv;        // [8 waves][64 rows]
    if (l15 == 0) {
#pragma unroll
        for (int mi = 0; mi < 4; ++mi)
#pragma unroll
            for (int r = 0; r < 4; ++r) {
                int row = mi * 16 + l4 * 4 + r;
                part[w * 64 + row] = psum[mi][r];
            }
    }
    __syncthreads();
    if (tid < 64) {
        float s = 0.f;
#pragma unroll
        for (int ww = 0; ww < 8; ++ww) s += part[ww * 64 + tid];
        score[rb + tid] = s + vb[0];
    }
}

// ---------------------------------------------------------------- K3: softmax over S per b
__global__ void k_softmax(const float* __restrict__ score, float* __restrict__ attn) {
    int b = blockIdx.x, tid = threadIdx.x;   // 32 blocks, 256 threads, 8 vals/thread
    float v[8];
    float m = -1e30f;
#pragma unroll
    for (int i = 0; i < 8; ++i) {
        v[i] = score[b * SS + i * 256 + tid];
        m = fmaxf(m, v[i]);
    }
#pragma unroll
    for (int mask = 1; mask < 64; mask <<= 1) m = fmaxf(m, __shfl_xor(m, mask));
    __shared__ float redm[4], reds[4];
    if ((tid & 63) == 0) redm[tid >> 6] = m;
    __syncthreads();
    m = fmaxf(fmaxf(redm[0], redm[1]), fmaxf(redm[2], redm[3]));
    float e[8], sum = 0.f;
#pragma unroll
    for (int i = 0; i < 8; ++i) { e[i] = expf(v[i] - m); sum += e[i]; }
#pragma unroll
    for (int mask = 1; mask < 64; mask <<= 1) sum += __shfl_xor(sum, mask);
    if ((tid & 63) == 0) reds[tid >> 6] = sum;
    __syncthreads();
    sum = reds[0] + reds[1] + reds[2] + reds[3];
    float inv = 1.0f / sum;
#pragma unroll
    for (int i = 0; i < 8; ++i) attn[b * SS + i * 256 + tid] = e[i] * inv;
}

// ---------------------------------------------------------------- K4: context partials = attn @ value (no atomics)
// 512 blocks = 32 b * 16 s-slices of 128 rows; partial[sl][b][1024] in ws.
__global__ void k_context(const float* __restrict__ attn, const float* __restrict__ value,
                          float* __restrict__ part) {
    int bid = blockIdx.x;
    int b = bid >> 4, sl = bid & 15;
    int tid = threadIdx.x;       // 256 threads -> 1024 d-cols via float4
    int s0 = sl * 128;
    const float4* vp = (const float4*)value + ((size_t)b * SS + s0) * 256 + tid;
    const float* ap = attn + b * SS + s0;
    float4 acc = make_float4(0.f, 0.f, 0.f, 0.f);
#pragma unroll 4
    for (int s = 0; s < 128; ++s) {
        float a = ap[s];
        float4 v = vp[(size_t)s * 256];
        acc.x = fmaf(a, v.x, acc.x);
        acc.y = fmaf(a, v.y, acc.y);
        acc.z = fmaf(a, v.z, acc.z);
        acc.w = fmaf(a, v.w, acc.w);
    }
    ((float4*)part)[((size_t)sl * BB + b) * 256 + tid] = acc;
}

// ---------------------------------------------------------------- K5: context = sum of 16 partials
__global__ void k_ctx_reduce(const float* __restrict__ part, float* __restrict__ context) {
    int i = blockIdx.x * 256 + threadIdx.x;  // 128 blocks -> 32768
    float s = 0.f;
#pragma unroll
    for (int j = 0; j < 16; ++j) s += part[(size_t)j * (BB * DIM) + i];
    context[i] = s;
}

// ----------------------------------------------------------------
extern "C" void kernel_launch(void* const* d_in, const int* in_sizes, int n_in,
                              void* d_out, int out_size, void* d_ws, size_t ws_size,
                              hipStream_t stream) {
    const float* query = (const float*)d_in[0];
    const float* key   = (const float*)d_in[1];
    const float* value = (const float*)d_in[2];
    const float* w1w   = (const float*)d_in[3];
    const float* w1b   = (const float*)d_in[4];
    const float* w2w   = (const float*)d_in[5];
    const float* w2b   = (const float*)d_in[6];
    const float* vw    = (const float*)d_in[7];
    const float* vb    = (const float*)d_in[8];

    float* out     = (float*)d_out;
    float* context = out;                 // [32,1024]
    float* attn    = out + BB * DIM;      // [32,2048]

    char* ws = (char*)d_ws;
    ushort_t* w2frag = (ushort_t*)ws;                                 // 2 MiB (dead after k_score)
    float* part      = (float*)ws;                                    // 2 MiB, reuses w2frag region
    float* qb        = (float*)(ws + (2u << 20));                     // 128 KiB
    float* score     = (float*)(ws + (2u << 20) + (128u << 10));      // 256 KiB

    k_w2frag<<<512, 256, 0, stream>>>(w2w, w2frag);
    k_qb<<<256, 256, 0, stream>>>(query, w1w, w1b, w2b, qb);
    k_score<<<1024, 512, 0, stream>>>(key, w2frag, qb, vw, vb, score);
    k_softmax<<<BB, 256, 0, stream>>>(score, attn);
    k_context<<<512, 256, 0, stream>>>(attn, value, part);
    k_ctx_reduce<<<128, 256, 0, stream>>>(part, context);
}